// Round 3
// baseline (510.274 us; speedup 1.0000x reference)
//
#include <hip/hip_runtime.h>
#include <stdint.h>

// Problem constants (fixed shapes from reference)
#define B_    4
#define QDIM  48
#define KDIM  160
#define HO    113            // KDIM - QDIM + 1
#define NQ    (QDIM*QDIM)    // 2304
#define NB    (KDIM*QDIM)    // 7680 band pixels (48 rows x 160 cols)
#define NR    (NB+NQ)        // 9984 merged entries
#define T_    384            // threads per block; NR / T_ = 26 exactly
#define NP    26             // entries per thread
#define NDIG  16

// swizzle for the radix count matrix to kill 32-way conflicts in the chunk scan
#define CIDX(l) ((l) + ((l) >> 5))

__device__ __forceinline__ uint32_t f2s(float v) {
  uint32_t u = __float_as_uint(v);
  uint32_t m = (u & 0x80000000u) ? 0xFFFFFFFFu : 0x80000000u;
  return u ^ m;
}
__device__ __forceinline__ float s2f(uint32_t s) {
  uint32_t m = (s & 0x80000000u) ? 0x80000000u : 0xFFFFFFFFu;
  return __uint_as_float(s ^ m);
}

__global__ void ps_init(unsigned long long* slots) {
  if (threadIdx.x < B_) slots[threadIdx.x] = ~0ULL;
}

__global__ __launch_bounds__(T_, 1)
void ps_band_kernel(const float* __restrict__ query,
                    const float* __restrict__ key,
                    unsigned long long* __restrict__ slots) {
  __shared__ uint32_t kA[NR];
  __shared__ uint32_t kB[NR];
  __shared__ uint8_t  pA[NR];
  __shared__ uint8_t  pB[NR];
  __shared__ uint32_t cnt[CIDX(NDIG*T_ - 1) + 2];
  __shared__ int      scanI[T_];
  __shared__ int      scanG[64];
  __shared__ float    scanF[T_];

  const int t  = threadIdx.x;
  const int b  = blockIdx.x / HO;
  const int oy = blockIdx.x % HO;
  const float* kp = key   + b * KDIM * KDIM;
  const float* qp = query + b * NQ;

  // ---- load band + query into kA/pA (payload: x coord, or 200 for query) ----
  for (int i = t; i < NR; i += T_) {
    uint32_t kk; uint8_t pp;
    if (i < NB) {
      int r = i / KDIM;
      int x = i - r * KDIM;
      kk = f2s(kp[(oy + r) * KDIM + x]);
      pp = (uint8_t)x;
    } else {
      kk = f2s(qp[i - NB]);
      pp = 200;
    }
    kA[i] = kk; pA[i] = pp;
  }
  __syncthreads();

  const int base = t * NP;
  const int t6   = t / 6;
  const int t6b  = t6 * 6;

  // ---- 8-pass 4-bit LSD radix sort (stable), key+payload ping-pong ----
  for (int p = 0; p < 8; ++p) {
    uint32_t* sK = (p & 1) ? kB : kA;
    uint32_t* dK = (p & 1) ? kA : kB;
    uint8_t*  sP = (p & 1) ? pB : pA;
    uint8_t*  dP = (p & 1) ? pA : pB;
    const int shift = p * 4;

    for (int i = t; i < NDIG * T_; i += T_) cnt[CIDX(i)] = 0;
    __syncthreads();

    for (int j = 0; j < NP; ++j) {
      uint32_t dg = (sK[base + j] >> shift) & 15u;
      cnt[CIDX(dg * T_ + t)] += 1;
    }
    __syncthreads();

    // local exclusive scan of this thread's 16 contiguous slots; chunk total -> scanI
    {
      int s = 0;
      const int cb = 16 * t;
      #pragma unroll
      for (int j = 0; j < 16; ++j) {
        int c = cnt[CIDX(cb + j)];
        cnt[CIDX(cb + j)] = s;
        s += c;
      }
      scanI[t] = s;
    }
    __syncthreads();

    // wave0 scans the 384 chunk totals (groups of 6 + 64-lane shfl scan)
    if (t < 64) {
      int s6 = 0;
      #pragma unroll
      for (int j = 0; j < 6; ++j) s6 += scanI[6 * t + j];
      int incl = s6;
      #pragma unroll
      for (int dl = 1; dl < 64; dl <<= 1) {
        int o = __shfl_up(incl, dl, 64);
        if (t >= dl) incl += o;
      }
      scanG[t] = incl - s6;   // exclusive base of group
    }
    __syncthreads();

    // add chunk base to the 16 local slots
    {
      int cbase = scanG[t6];
      for (int j = t6b; j < t; ++j) cbase += scanI[j];
      const int cb = 16 * t;
      #pragma unroll
      for (int j = 0; j < 16; ++j) cnt[CIDX(cb + j)] += cbase;
    }
    __syncthreads();

    // stable scatter
    for (int j = 0; j < NP; ++j) {
      uint32_t k  = sK[base + j];
      uint32_t dg = (k >> shift) & 15u;
      uint32_t pos = cnt[CIDX(dg * T_ + t)];
      cnt[CIDX(dg * T_ + t)] = pos + 1;
      dK[pos] = k;
      dP[pos] = sP[base + j];
    }
    __syncthreads();
  }
  // sorted result in kA (keys) / pA (payload)

  // ---- preload this thread's 26 entries into registers: gap + payload byte ----
  float g[NP];
  int   xb[NP];
  #pragma unroll
  for (int j = 0; j < NP; ++j) {
    int i = base + j;
    uint32_t k0 = kA[i];
    uint32_t k1 = (i + 1 < NR) ? kA[i + 1] : k0;
    float v0 = s2f(k0), v1 = s2f(k1);
    g[j]  = (i < NR - 1) ? (v1 - v0) : 0.0f;
    xb[j] = pA[i];
  }
  __syncthreads();

  // ---- per-ox evaluation: y*n = sum |prefix(d)| * gap ----
  float bestY = 3.4e38f;
  int   bestOx = 0;

  for (int ox = 0; ox < HO; ++ox) {
    // phase A: per-thread signed count over its chunk
    int partial = 0;
    #pragma unroll
    for (int j = 0; j < NP; ++j) {
      int x = xb[j];
      int d = (x < KDIM) ? (((unsigned)(x - ox) < (unsigned)QDIM) ? 1 : 0) : -1;
      partial += d;
    }
    scanI[t] = partial;
    __syncthreads();

    if (t < 64) {
      int s6 = 0;
      #pragma unroll
      for (int j = 0; j < 6; ++j) s6 += scanI[6 * t + j];
      int incl = s6;
      #pragma unroll
      for (int dl = 1; dl < 64; dl <<= 1) {
        int o = __shfl_up(incl, dl, 64);
        if (t >= dl) incl += o;
      }
      scanG[t] = incl - s6;
    }
    __syncthreads();

    int s = scanG[t6];
    for (int j = t6b; j < t; ++j) s += scanI[j];

    // phase B: walk chunk, accumulate |s| * gap
    float acc = 0.0f;
    #pragma unroll
    for (int j = 0; j < NP; ++j) {
      int x = xb[j];
      int d = (x < KDIM) ? (((unsigned)(x - ox) < (unsigned)QDIM) ? 1 : 0) : -1;
      s += d;
      acc = fmaf(fabsf((float)s), g[j], acc);
    }
    scanF[t] = acc;
    __syncthreads();

    if (t < 64) {
      float r = 0.f;
      #pragma unroll
      for (int j = 0; j < 6; ++j) r += scanF[6 * t + j];
      #pragma unroll
      for (int dl = 32; dl >= 1; dl >>= 1) r += __shfl_xor(r, dl, 64);
      if (t == 0 && r < bestY) { bestY = r; bestOx = ox; }
    }
    __syncthreads();
  }

  if (t == 0) {
    unsigned long long pk =
      (((unsigned long long)__float_as_uint(bestY)) << 32) |
      (unsigned long long)(unsigned)(oy * HO + bestOx);
    atomicMin(&slots[b], pk);
  }
}

__global__ void ps_final(const unsigned long long* __restrict__ slots,
                         int* __restrict__ out) {
  int t = threadIdx.x;
  if (t < B_) out[t] = (int)(unsigned)(slots[t] & 0xFFFFFFFFull);
  if (t == B_) out[t] = HO;
}

extern "C" void kernel_launch(void* const* d_in, const int* in_sizes, int n_in,
                              void* d_out, int out_size, void* d_ws, size_t ws_size,
                              hipStream_t stream) {
  const float* query = (const float*)d_in[0];   // [4,1,48,48]
  const float* key   = (const float*)d_in[1];   // [4,1,160,160]
  unsigned long long* slots = (unsigned long long*)d_ws;
  int* out = (int*)d_out;

  hipLaunchKernelGGL(ps_init, dim3(1), dim3(64), 0, stream, slots);
  hipLaunchKernelGGL(ps_band_kernel, dim3(B_ * HO), dim3(T_), 0, stream,
                     query, key, slots);
  hipLaunchKernelGGL(ps_final, dim3(1), dim3(64), 0, stream, slots, out);
}

// Round 6
// 292.259 us; speedup vs baseline: 1.7460x; 1.7460x over previous
//
#include <hip/hip_runtime.h>
#include <stdint.h>

#define B_    4
#define QDIM  48
#define KDIM  160
#define HO    113            // KDIM - QDIM + 1
#define NQ    (QDIM*QDIM)    // 2304
#define NB    (KDIM*QDIM)    // 7680
#define NR    (NB+NQ)        // 9984 real entries
#define T_    1024           // 16 waves
#define NW    16
#define NP    10             // entries/thread (padded to NPAD)
#define NPAD  10240          // 1024*10, multiple of 1024
#define NCH   10             // chunks of 1024 entries
#define NPAIR 57             // ceil(113/2)

// swizzle for u16 count array: kills the 16-way conflict in the blocked scan
#define CIDX16(f) ((f) + ((f) >> 4))
// size: CIDX16(16*1024-1)+1 = 17407 -> 17408

__device__ __forceinline__ uint32_t f2s(float v) {
  uint32_t u = __float_as_uint(v);
  return u ^ ((u & 0x80000000u) ? 0xFFFFFFFFu : 0x80000000u);
}
__device__ __forceinline__ float s2f(uint32_t s) {
  return __uint_as_float(s ^ ((s & 0x80000000u) ? 0x80000000u : 0xFFFFFFFFu));
}

__global__ void ps_init(unsigned long long* slots) {
  if (threadIdx.x < B_) slots[threadIdx.x] = ~0ULL;
}

__global__ __launch_bounds__(T_)
void ps_band_kernel(const float* __restrict__ query,
                    const float* __restrict__ key,
                    unsigned long long* __restrict__ slots) {
  // E (80KB) doubles as kA|kB during the sort (exactly 2*NPAD u32)
  __shared__ unsigned long long E[NPAD];
  __shared__ uint8_t  pA[NPAD];
  __shared__ uint8_t  pB[NPAD];
  __shared__ uint16_t cnt[17408];
  __shared__ int      waveTot[NW], waveBase[NW];
  __shared__ unsigned long long wbest[NW];

  uint32_t* kA = (uint32_t*)E;
  uint32_t* kB = kA + NPAD;

  const int t    = threadIdx.x;
  const int lane = t & 63;
  const int w    = t >> 6;
  const int b    = blockIdx.x / HO;
  const int oy   = blockIdx.x % HO;
  const float* kp = key   + b * KDIM * KDIM;
  const float* qp = query + b * NQ;

  // ---- load band + query (+pad) ----
  for (int i = t; i < NPAD; i += T_) {
    uint32_t kk, pp;
    if (i < NB) {
      int r = i / KDIM; int x = i - r * KDIM;
      kk = f2s(kp[(oy + r) * KDIM + x]); pp = (uint32_t)x;
    } else if (i < NR) {
      kk = f2s(qp[i - NB]); pp = 255u;        // query sentinel (d=-1)
    } else {
      kk = 0xFFFFFFFFu; pp = 254u;            // pad sentinel (d=0, gap=0)
    }
    kA[i] = kk; pA[i] = (uint8_t)pp;
  }
  __syncthreads();

  const int base = t * NP;

  // ---- 8-pass 4-bit LSD radix sort, register-staged, u16 counts ----
  for (int p = 0; p < 8; ++p) {
    uint32_t* sK = (p & 1) ? kB : kA;
    uint32_t* dK = (p & 1) ? kA : kB;
    uint8_t*  sP = (p & 1) ? pB : pA;
    uint8_t*  dP = (p & 1) ? pA : pB;
    const int sh = p * 4;

    for (int i = t; i < 8704; i += T_) ((uint32_t*)cnt)[i] = 0;
    __syncthreads();

    uint32_t kreg[NP]; uint32_t preg[NP];
    #pragma unroll
    for (int j = 0; j < NP; ++j) { kreg[j] = sK[base + j]; preg[j] = sP[base + j]; }

    #pragma unroll
    for (int j = 0; j < NP; ++j) {
      uint32_t f = CIDX16(((kreg[j] >> sh) & 15u) * T_ + t);
      cnt[f] = (uint16_t)(cnt[f] + 1);
    }
    __syncthreads();

    // blocked flat scan: 16 slots/thread in regs
    uint32_t cex[16]; int s = 0;
    #pragma unroll
    for (int j = 0; j < 16; ++j) { int c = cnt[CIDX16(16 * t + j)]; cex[j] = (uint32_t)s; s += c; }

    int incl = s;
    #pragma unroll
    for (int d = 1; d < 64; d <<= 1) { int o = __shfl_up(incl, d, 64); if (lane >= d) incl += o; }
    if (lane == 63) waveTot[w] = incl;
    const int wexcl = incl - s;
    __syncthreads();
    if (t < NW) {
      int v = waveTot[t]; int iw = v;
      #pragma unroll
      for (int d = 1; d < NW; d <<= 1) { int o = __shfl_up(iw, d, NW); if (t >= d) iw += o; }
      waveBase[t] = iw - v;
    }
    __syncthreads();
    const int tb = waveBase[w] + wexcl;
    #pragma unroll
    for (int j = 0; j < 16; ++j) cnt[CIDX16(16 * t + j)] = (uint16_t)(cex[j] + (uint32_t)tb);
    __syncthreads();

    // stable scatter
    #pragma unroll
    for (int j = 0; j < NP; ++j) {
      uint32_t f = CIDX16(((kreg[j] >> sh) & 15u) * T_ + t);
      uint32_t pos = cnt[f];
      cnt[f] = (uint16_t)(pos + 1);
      dK[pos] = kreg[j];
      dP[pos] = (uint8_t)preg[j];
    }
    __syncthreads();
  }
  // sorted: keys in kA, payload in pA

  // ---- build packed (gap,x) stream E in bank-transposed layout ----
  // logical entry i: chunk c=i>>10, l=(i>>4)&63, sub=(i>>1)&7, q=i&1
  // phys u64 idx = c*1024 + sub*128 + l*2 + q  (per-instr reads cover all 32 banks)
  {
    uint32_t kk2[NP + 1]; uint32_t pp2[NP];
    #pragma unroll
    for (int j = 0; j < NP; ++j) { kk2[j] = kA[base + j]; pp2[j] = pA[base + j]; }
    kk2[NP] = (t == T_ - 1) ? 0xFFFFFFFFu : kA[base + NP];
    __syncthreads();   // everyone staged before E overwrites kA/kB
    #pragma unroll
    for (int j = 0; j < NP; j += 2) {
      int i = base + j;                          // even
      float g0 = (i     < NR - 1) ? s2f(kk2[j + 1]) - s2f(kk2[j])     : 0.0f;
      float g1 = (i + 1 < NR - 1) ? s2f(kk2[j + 2]) - s2f(kk2[j + 1]) : 0.0f;
      int c = i >> 10, e = i & 1023;
      int l = e >> 4, sb = (e >> 1) & 7;
      int pidx = c * 1024 + sb * 128 + l * 2;
      E[pidx]     = (unsigned long long)__float_as_uint(g0) | ((unsigned long long)pp2[j]     << 32);
      E[pidx + 1] = (unsigned long long)__float_as_uint(g1) | ((unsigned long long)pp2[j + 1] << 32);
    }
    __syncthreads();
  }

  // ---- eval: one ox-PAIR per wave, zero block barriers ----
  unsigned long long mybest = ~0ULL;
  for (int pr = w; pr < NPAIR; pr += NW) {
    const int oxa = 2 * pr, oxb = 2 * pr + 1;   // oxb==113 invalid at pr==56
    float carry_a = 0.f, carry_b = 0.f, acc_a = 0.f, acc_b = 0.f;
    for (int c = 0; c < NCH; ++c) {
      float ga[16], pa_[16], pb_[16];
      float ra = 0.f, rb = 0.f;
      const unsigned long long* Ep = E + (c * 1024 + lane * 2);
      #pragma unroll
      for (int sb = 0; sb < 8; ++sb) {
        unsigned long long e0 = Ep[sb * 128];
        unsigned long long e1 = Ep[sb * 128 + 1];
        {
          uint32_t x = (uint32_t)(e0 >> 32);
          float gg = __uint_as_float((uint32_t)e0);
          float d0 = (x == 255u) ? -1.0f : 0.0f;
          float da = ((uint32_t)(x - (uint32_t)oxa) < (uint32_t)QDIM) ? 1.0f : d0;
          float db = ((uint32_t)(x - (uint32_t)oxb) < (uint32_t)QDIM) ? 1.0f : d0;
          ra += da; rb += db;
          ga[2 * sb] = gg; pa_[2 * sb] = ra; pb_[2 * sb] = rb;
        }
        {
          uint32_t x = (uint32_t)(e1 >> 32);
          float gg = __uint_as_float((uint32_t)e1);
          float d0 = (x == 255u) ? -1.0f : 0.0f;
          float da = ((uint32_t)(x - (uint32_t)oxa) < (uint32_t)QDIM) ? 1.0f : d0;
          float db = ((uint32_t)(x - (uint32_t)oxb) < (uint32_t)QDIM) ? 1.0f : d0;
          ra += da; rb += db;
          ga[2 * sb + 1] = gg; pa_[2 * sb + 1] = ra; pb_[2 * sb + 1] = rb;
        }
      }
      // cross-lane exclusive scan of lane totals
      float ia = ra, ib = rb;
      #pragma unroll
      for (int d = 1; d < 64; d <<= 1) {
        float oa = __shfl_up(ia, d, 64);
        float ob = __shfl_up(ib, d, 64);
        if (lane >= d) { ia += oa; ib += ob; }
      }
      const float basea = carry_a + ia - ra;
      const float baseb = carry_b + ib - rb;
      carry_a += __shfl(ia, 63, 64);
      carry_b += __shfl(ib, 63, 64);
      #pragma unroll
      for (int j = 0; j < 16; ++j) {
        acc_a = fmaf(fabsf(basea + pa_[j]), ga[j], acc_a);
        acc_b = fmaf(fabsf(baseb + pb_[j]), ga[j], acc_b);
      }
    }
    // wave total
    #pragma unroll
    for (int d = 32; d >= 1; d >>= 1) {
      acc_a += __shfl_xor(acc_a, d, 64);
      acc_b += __shfl_xor(acc_b, d, 64);
    }
    if (lane == 0) {
      unsigned long long ca =
        (((unsigned long long)__float_as_uint(acc_a)) << 32) | (unsigned)(oy * HO + oxa);
      if (ca < mybest) mybest = ca;
      if (oxb < HO) {
        unsigned long long cb =
          (((unsigned long long)__float_as_uint(acc_b)) << 32) | (unsigned)(oy * HO + oxb);
        if (cb < mybest) mybest = cb;
      }
    }
  }

  if (lane == 0) wbest[w] = mybest;
  __syncthreads();
  if (t == 0) {
    unsigned long long m = wbest[0];
    #pragma unroll
    for (int i = 1; i < NW; ++i) m = (wbest[i] < m) ? wbest[i] : m;
    atomicMin(slots + b, m);
  }
}

__global__ void ps_final(const unsigned long long* __restrict__ slots,
                         int* __restrict__ out) {
  int t = threadIdx.x;
  if (t < B_) out[t] = (int)(unsigned)(slots[t] & 0xFFFFFFFFull);
  if (t == B_) out[t] = HO;
}

extern "C" void kernel_launch(void* const* d_in, const int* in_sizes, int n_in,
                              void* d_out, int out_size, void* d_ws, size_t ws_size,
                              hipStream_t stream) {
  const float* query = (const float*)d_in[0];   // [4,1,48,48]
  const float* key   = (const float*)d_in[1];   // [4,1,160,160]
  unsigned long long* slots = (unsigned long long*)d_ws;
  int* out = (int*)d_out;

  hipLaunchKernelGGL(ps_init, dim3(1), dim3(64), 0, stream, slots);
  hipLaunchKernelGGL(ps_band_kernel, dim3(B_ * HO), dim3(T_), 0, stream,
                     query, key, slots);
  hipLaunchKernelGGL(ps_final, dim3(1), dim3(64), 0, stream, slots, out);
}